// Round 12
// baseline (449.798 us; speedup 1.0000x reference)
//
#include <hip/hip_runtime.h>

// out = (((x + 2) * 3 - 5) / 4)^2 == ((3x + 1) * 0.25)^2, elementwise fp32.
// 8192*8192 = 67108864 elements -> 256 MiB in + 256 MiB out = 537 MB HBM traffic.
// Pure streaming: kernel roofline ~85 us at the ~6.4 TB/s this chip measures
// (harness poison-fills hit 6.34-6.50 TB/s = 79-81% of peak, plain stores).
//
// Evidence from Round 11 (first successful bench, dur_us=443.2):
//  - Top-5 dispatches are all 1 GiB harness fills (~166 us each); ew_kernel
//    is below them -> kernel GPU time < 165 us. Bench dur_us is dominated
//    by ~330 us of harness reset fills, not the kernel.
//  - Fills prove plain (cached) stores reach 6.4 TB/s at 10% occupancy.
//  - Cross-session dur_us rose 410.8 -> 443.2; only memory-path delta in
//    this version was the `nt` flag. Hypothesis: nt stores hurt write BW.
// This round's single delta: REMOVE nontemporal hints (plain loads/stores).
// Keep grid-stride persistent waves + 4-way unroll (strictly more MLP).

typedef float f4 __attribute__((ext_vector_type(4)));

__device__ __forceinline__ f4 ew_op(f4 v) {
    // r = (3x + 1) * 0.25; out = r*r  (fp-contract folds mul+add to v_fma)
    f4 r = (v * 3.0f + 1.0f) * 0.25f;
    return r * r;
}

__global__ __launch_bounds__(256) void ew_kernel(const f4* __restrict__ in,
                                                 f4* __restrict__ out,
                                                 int n4) {
    int T = gridDim.x * blockDim.x;
    int i = blockIdx.x * blockDim.x + threadIdx.x;
    // 4-way unrolled main loop: all four loads issued before any store.
    for (; i + 3 * T < n4; i += 4 * T) {
        f4 v0 = in[i];
        f4 v1 = in[i + T];
        f4 v2 = in[i + 2 * T];
        f4 v3 = in[i + 3 * T];
        out[i]         = ew_op(v0);
        out[i + T]     = ew_op(v1);
        out[i + 2 * T] = ew_op(v2);
        out[i + 3 * T] = ew_op(v3);
    }
    // Cleanup: remaining grid-stride iterations.
    for (; i < n4; i += T) {
        out[i] = ew_op(in[i]);
    }
}

// Scalar tail for generality (n % 4 == 0 for 8192^2, so normally not launched).
__global__ void ew_tail(const float* __restrict__ in, float* __restrict__ out,
                        int start, int n) {
    int i = start + blockIdx.x * blockDim.x + threadIdx.x;
    if (i < n) {
        float r = fmaf(3.0f, in[i], 1.0f) * 0.25f;
        out[i] = r * r;
    }
}

extern "C" void kernel_launch(void* const* d_in, const int* in_sizes, int n_in,
                              void* d_out, int out_size, void* d_ws, size_t ws_size,
                              hipStream_t stream) {
    const float* in = (const float*)d_in[0];
    float* out = (float*)d_out;
    int n = in_sizes[0];

    int n4 = n / 4;
    if (n4 > 0) {
        const int threads = 256;
        int blocks = (n4 + threads - 1) / threads;
        const int max_blocks = 2048;  // 256 CUs x 8 blocks/CU, grid-stride the rest
        if (blocks > max_blocks) blocks = max_blocks;
        ew_kernel<<<blocks, threads, 0, stream>>>((const f4*)in, (f4*)out, n4);
    }
    int rem = n - n4 * 4;
    if (rem > 0) {
        ew_tail<<<1, 64, 0, stream>>>(in, out, n4 * 4, n);
    }
}

// Round 16
// 414.250 us; speedup vs baseline: 1.0858x; 1.0858x over previous
//
#include <hip/hip_runtime.h>

// out = (((x + 2) * 3 - 5) / 4)^2 == ((3x + 1) * 0.25)^2, elementwise fp32.
// 8192*8192 = 67108864 elements -> 256 MiB in + 256 MiB out = 537 MB HBM traffic.
// Roofline: ~83 us at the ~6.45 TB/s this chip measures (harness fills hit
// 6.4-6.5 TB/s = 80-81% of peak).
//
// Evidence ledger (rounds 11-12):
//  - Bench dur_us is fill-dominated: top-5 dispatches are 1 GiB harness
//    poison-fills (~165 us each); decomposition = 2 fills (~330 us) + kernel.
//  - Prior-session flat one-shot kernel: 410.8 total -> ~80 us kernel
//    == HBM roofline already. The "flat kernel = 1.3 TB/s" premise was a
//    misread of fill-dominated dur_us.
//  - Grid-stride + x4 unroll (rounds 11/12): 443-450 total -> ~113-120 us
//    kernel (~4.7 TB/s) — persistent-wave loop was a REGRESSION. One-shot
//    wave churn already maximizes MLP (fills: 6.5 TB/s at 10% occupancy);
//    the loop added backedge overhead + intra-wave vmcnt coupling.
//  - nt vs plain: 443.2 vs 449.8 — noise; nt irrelevant.
// This round: revert to flat one-shot float4 kernel (single delta, re-sent
// after infra failure).

__global__ __launch_bounds__(256) void ew_kernel(const float4* __restrict__ in,
                                                 float4* __restrict__ out,
                                                 int n4) {
    int i = blockIdx.x * blockDim.x + threadIdx.x;
    if (i < n4) {
        float4 v = in[i];
        float4 r;
        // r = (3x + 1) * 0.25; out = r*r
        float a = fmaf(3.0f, v.x, 1.0f) * 0.25f;
        float b = fmaf(3.0f, v.y, 1.0f) * 0.25f;
        float c = fmaf(3.0f, v.z, 1.0f) * 0.25f;
        float d = fmaf(3.0f, v.w, 1.0f) * 0.25f;
        r.x = a * a;
        r.y = b * b;
        r.z = c * c;
        r.w = d * d;
        out[i] = r;
    }
}

// Scalar tail for generality (n % 4 == 0 for 8192^2, so normally not launched).
__global__ void ew_tail(const float* __restrict__ in, float* __restrict__ out,
                        int start, int n) {
    int i = start + blockIdx.x * blockDim.x + threadIdx.x;
    if (i < n) {
        float r = fmaf(3.0f, in[i], 1.0f) * 0.25f;
        out[i] = r * r;
    }
}

extern "C" void kernel_launch(void* const* d_in, const int* in_sizes, int n_in,
                              void* d_out, int out_size, void* d_ws, size_t ws_size,
                              hipStream_t stream) {
    const float* in = (const float*)d_in[0];
    float* out = (float*)d_out;
    int n = in_sizes[0];

    int n4 = n / 4;
    if (n4 > 0) {
        int threads = 256;
        int blocks = (n4 + threads - 1) / threads;
        ew_kernel<<<blocks, threads, 0, stream>>>((const float4*)in, (float4*)out, n4);
    }
    int rem = n - n4 * 4;
    if (rem > 0) {
        ew_tail<<<1, 64, 0, stream>>>(in, out, n4 * 4, n);
    }
}